// Round 12
// baseline (587.770 us; speedup 1.0000x reference)
//
#include <hip/hip_runtime.h>
#include <math.h>

// Problem constants (fixed by setup_inputs)
constexpr int Bc = 256, Sc = 1024, Dc = 32, Kc = 512;
constexpr int ST = 128;                      // s-rows per main block
constexpr float LOG2E    = 1.4426950408889634f;
constexpr float LN2      = 0.6931471805599453f;
constexpr float LOG_NORM = 29.40603306051f;  // D * 0.5 * log(2*pi)

typedef __attribute__((ext_vector_type(16))) float f32x16;

#if __has_builtin(__builtin_amdgcn_exp2f)
#define EXP2F(v) __builtin_amdgcn_exp2f(v)
#else
#define EXP2F(v) exp2f(v)
#endif
#if __has_builtin(__builtin_amdgcn_logf)
#define LOG2F(v) __builtin_amdgcn_logf(v)
#else
#define LOG2F(v) log2f(v)
#endif

// pack 2 f32 -> 2 e4m3 bytes; word_sel is a template constant.
template <bool HI>
__device__ __forceinline__ int pkfp8(float a, float b, int old) {
    return __builtin_amdgcn_cvt_pk_fp8_f32(a, b, old, HI);
}

// ---------------- tiny prep: means -> e4m3 + m2buf[512] ----------------
__global__ __launch_bounds__(256)
void gm_m2f8(const float* __restrict__ means,
             unsigned short* __restrict__ mf8, float* __restrict__ m2buf)
{
    const int t  = blockIdx.x * 256 + threadIdx.x;   // 0..8191 (pairs)
    const float v0 = means[2 * t];
    const float v1 = means[2 * t + 1];
    mf8[t] = (unsigned short)(pkfp8<false>(v0, v1, 0) & 0xffff);
    float sq = v0 * v0 + v1 * v1;
    #pragma unroll
    for (int off = 1; off <= 8; off <<= 1) sq += __shfl_xor(sq, off);
    if ((threadIdx.x & 15) == 0) m2buf[t >> 4] = sq;   // 16 pair-threads per row
}

// ---------------- main kernel: 32x32x16 fp8, chained K ----------------
// grid(2048), 256 threads = 4 waves; wave owns ONE 32-row tile.
// K-loop fully unrolled (16 iters x 32 k-cols), zero in-loop addr math.
//   acc = sum_k w_k * 2^((x*log2e).mu_k),  w_k = 2^((l_k-0.5*m2_k)*log2e)
//   nll = 0.5*x^2 + LOG_NORM + lse - ln2*log2(acc)
__global__ __launch_bounds__(256, 8)
void gm_main(const float* __restrict__ x, const float* __restrict__ logits,
             const float* __restrict__ m2buf, const unsigned short* __restrict__ mf8,
             float* __restrict__ out)
{
    __shared__ unsigned char mlds[Kc * 32];   // 16 KB e4m3 means, chunk-XOR swizzled
    __shared__ float wlds[Kc];                //  2 KB unnormalized weights
    __shared__ float x2p[ST];                 // 0.5 KB per-row sum(x^2)
    __shared__ float red[8];

    const int tid  = threadIdx.x;
    const int lane = tid & 63;
    const int wid  = tid >> 6;
    const int b    = blockIdx.x >> 3;
    const int s0   = (blockIdx.x & 7) * ST;
    const int n    = lane & 31;               // col within k-tile / row within s-tile
    const int h    = lane >> 5;               // K-half selector
    const int rw   = wid * 32;

    // stage means: 16 KB coalesced copy; 8B chunk c of row r at c ^ ((r>>2)&3)
    {
        const unsigned long long* src = (const unsigned long long*)mf8;
        #pragma unroll
        for (int j = 0; j < 8; ++j) {
            const int c = tid + j * 256;       // 8B-chunk index 0..2047
            const int r = c >> 2, ch = c & 3;
            *(unsigned long long*)&mlds[r * 32 + ((ch ^ ((r >> 2) & 3)) << 3)] = src[c];
        }
    }

    // in-block unnormalized weights + start of lse
    const float l0 = logits[b * Kc + tid];
    const float l1 = logits[b * Kc + tid + 256];
    wlds[tid]       = EXP2F((l0 - 0.5f * m2buf[tid])       * LOG2E);
    wlds[tid + 256] = EXP2F((l1 - 0.5f * m2buf[tid + 256]) * LOG2E);

    float mx = fmaxf(l0, l1);
    #pragma unroll
    for (int off = 32; off >= 1; off >>= 1) mx = fmaxf(mx, __shfl_xor(mx, off));
    if (lane == 0) red[wid] = mx;

    // x A-fragments: row = rw + n; lane covers floats [8h..8h+7] (lo) and
    // [16+8h..16+8h+7] (hi). Union over h = full row.
    const int row = rw + n;
    long a_lo, a_hi;
    float p;
    {
        const float4* xr = (const float4*)(x + ((size_t)b * Sc + s0 + row) * Dc);
        float4 v0 = xr[2 * h], v1 = xr[2 * h + 1];        // lo half
        float4 w0 = xr[4 + 2 * h], w1 = xr[5 + 2 * h];    // hi half
        int2 A;
        A.x = pkfp8<false>(v0.x * LOG2E, v0.y * LOG2E, 0);
        A.x = pkfp8<true >(v0.z * LOG2E, v0.w * LOG2E, A.x);
        A.y = pkfp8<false>(v1.x * LOG2E, v1.y * LOG2E, 0);
        A.y = pkfp8<true >(v1.z * LOG2E, v1.w * LOG2E, A.y);
        a_lo = *(const long*)&A;
        A.x = pkfp8<false>(w0.x * LOG2E, w0.y * LOG2E, 0);
        A.x = pkfp8<true >(w0.z * LOG2E, w0.w * LOG2E, A.x);
        A.y = pkfp8<false>(w1.x * LOG2E, w1.y * LOG2E, 0);
        A.y = pkfp8<true >(w1.z * LOG2E, w1.w * LOG2E, A.y);
        a_hi = *(const long*)&A;
        p = v0.x*v0.x + v0.y*v0.y + v0.z*v0.z + v0.w*v0.w
          + v1.x*v1.x + v1.y*v1.y + v1.z*v1.z + v1.w*v1.w
          + w0.x*w0.x + w0.y*w0.y + w0.z*w0.z + w0.w*w0.w
          + w1.x*w1.x + w1.y*w1.y + w1.z*w1.z + w1.w*w1.w;
        p += __shfl_xor(p, 32);               // combine the two K-halves
        if (h == 0) x2p[row] = p;
    }
    __syncthreads();

    // finish lse (max across waves parked in red[0..3])
    const float mxb = fmaxf(fmaxf(red[0], red[1]), fmaxf(red[2], red[3]));
    float sm = EXP2F((l0 - mxb) * LOG2E) + EXP2F((l1 - mxb) * LOG2E);
    #pragma unroll
    for (int off = 32; off >= 1; off >>= 1) sm += __shfl_xor(sm, off);
    if (lane == 0) red[4 + wid] = sm;

    // preload this lane's 16 weights (col = kt*32 + n; conflict-free, bcast x2)
    float wreg[16];
    #pragma unroll
    for (int kt = 0; kt < 16; ++kt) wreg[kt] = wlds[kt * 32 + n];

    // B-frag base addrs: row n, logical chunk h (lo) / 2+h (hi), XOR (n>>2)&3.
    // kt advances by 32 rows * 32 B = 1024 B -> 16-bit immediate offsets.
    const int s  = (n >> 2) & 3;
    const int vlo = n * 32 + ((h ^ s) << 3);
    const int vhi = vlo ^ 16;                 // chunk (2+h)^s = (h^s)^2 -> ^16 bytes

    const f32x16 zero = {0.f,0.f,0.f,0.f,0.f,0.f,0.f,0.f,
                         0.f,0.f,0.f,0.f,0.f,0.f,0.f,0.f};
    float acc[16] = {};

    #pragma unroll
    for (int kt = 0; kt < 16; ++kt) {
        const long b_lo = *(const long*)&mlds[vlo + kt * 1024];
        const long b_hi = *(const long*)&mlds[vhi + kt * 1024];
        f32x16 d = __builtin_amdgcn_mfma_f32_32x32x16_fp8_fp8(a_lo, b_lo, zero, 0, 0, 0);
        d = __builtin_amdgcn_mfma_f32_32x32x16_fp8_fp8(a_hi, b_hi, d, 0, 0, 0);
        const float wv = wreg[kt];
        #pragma unroll
        for (int r = 0; r < 16; ++r)
            acc[r] = fmaf(wv, EXP2F(d[r]), acc[r]);
    }
    __syncthreads();                          // red[4..7] ready
    const float lse  = mxb + LN2 * LOG2F(red[4] + red[5] + red[6] + red[7]);
    const float base = LOG_NORM + lse;

    // epilogue: sum over 32 k-cols (lanes within each 32-half), write 32 rows.
    // C/D: col=lane&31, row m = (r&3) + 8*(r>>2) + 4*h
    #pragma unroll
    for (int r = 0; r < 16; ++r) {
        float v = acc[r];
        v += __shfl_xor(v, 1); v += __shfl_xor(v, 2);
        v += __shfl_xor(v, 4); v += __shfl_xor(v, 8); v += __shfl_xor(v, 16);
        if (n == 0) {
            const int m = (r & 3) + 8 * (r >> 2) + 4 * h;
            out[(size_t)b * Sc + s0 + rw + m] =
                0.5f * x2p[rw + m] + base - LN2 * LOG2F(v);
        }
    }
}

extern "C" void kernel_launch(void* const* d_in, const int* in_sizes, int n_in,
                              void* d_out, int out_size, void* d_ws, size_t ws_size,
                              hipStream_t stream) {
    const float* x      = (const float*)d_in[0];
    const float* logits = (const float*)d_in[1];
    const float* means  = (const float*)d_in[2];
    float* out = (float*)d_out;
    (void)in_sizes; (void)n_in; (void)out_size; (void)ws_size;

    unsigned short* mf8   = (unsigned short*)d_ws;             // 16 KB (8192 u16)
    float*          m2buf = (float*)((char*)d_ws + 16384);     //  2 KB

    hipLaunchKernelGGL(gm_m2f8, dim3(32), dim3(256), 0, stream, means, mf8, m2buf);
    hipLaunchKernelGGL(gm_main, dim3(Bc * (Sc / ST)), dim3(256), 0, stream,
                       x, logits, m2buf, mf8, out);
}

// Round 13
// 94.663 us; speedup vs baseline: 6.2091x; 6.2091x over previous
//
#include <hip/hip_runtime.h>
#include <math.h>

// Problem constants (fixed by setup_inputs)
constexpr int Bc = 256, Sc = 1024, Dc = 32, Kc = 512;
constexpr int ST = 128;                      // s-rows per main block
constexpr float LOG2E    = 1.4426950408889634f;
constexpr float LN2      = 0.6931471805599453f;
constexpr float LOG_NORM = 29.40603306051f;  // D * 0.5 * log(2*pi)

typedef __attribute__((ext_vector_type(16))) float f32x16;

#if __has_builtin(__builtin_amdgcn_exp2f)
#define EXP2F(v) __builtin_amdgcn_exp2f(v)
#else
#define EXP2F(v) exp2f(v)
#endif
#if __has_builtin(__builtin_amdgcn_logf)
#define LOG2F(v) __builtin_amdgcn_logf(v)
#else
#define LOG2F(v) log2f(v)
#endif

// pack 2 f32 -> 2 e4m3 bytes; word_sel is a template constant.
template <bool HI>
__device__ __forceinline__ int pkfp8(float a, float b, int old) {
    return __builtin_amdgcn_cvt_pk_fp8_f32(a, b, old, HI);
}

// ---------------- tiny prep: means -> e4m3 + m2buf[512] ----------------
__global__ __launch_bounds__(256)
void gm_m2f8(const float* __restrict__ means,
             unsigned short* __restrict__ mf8, float* __restrict__ m2buf)
{
    const int t  = blockIdx.x * 256 + threadIdx.x;   // 0..8191 (pairs)
    const float v0 = means[2 * t];
    const float v1 = means[2 * t + 1];
    mf8[t] = (unsigned short)(pkfp8<false>(v0, v1, 0) & 0xffff);
    float sq = v0 * v0 + v1 * v1;
    #pragma unroll
    for (int off = 1; off <= 8; off <<= 1) sq += __shfl_xor(sq, off);
    if ((threadIdx.x & 15) == 0) m2buf[t >> 4] = sq;   // 16 pair-threads per row
}

// ---------------- main kernel: 32x32x16 fp8, chained K ----------------
// grid(2048), 256 threads = 4 waves; wave owns ONE 32-row tile.
// (256,6): ~84 VGPR budget -> no spill (R12's (256,8) spilled to 2 GB scratch).
//   acc = sum_k w_k * 2^((x*log2e).mu_k),  w_k = 2^((l_k-0.5*m2_k)*log2e)
//   nll = 0.5*x^2 + LOG_NORM + lse - ln2*log2(acc)
__global__ __launch_bounds__(256, 6)
void gm_main(const float* __restrict__ x, const float* __restrict__ logits,
             const float* __restrict__ m2buf, const unsigned short* __restrict__ mf8,
             float* __restrict__ out)
{
    __shared__ unsigned char mlds[Kc * 32];   // 16 KB e4m3 means, chunk-XOR swizzled
    __shared__ float wlds[Kc];                //  2 KB unnormalized weights
    __shared__ float x2p[ST];                 // 0.5 KB per-row sum(x^2)
    __shared__ float red[8];

    const int tid  = threadIdx.x;
    const int lane = tid & 63;
    const int wid  = tid >> 6;
    const int b    = blockIdx.x >> 3;
    const int s0   = (blockIdx.x & 7) * ST;
    const int n    = lane & 31;               // col within k-tile / row within s-tile
    const int h    = lane >> 5;               // K-half selector
    const int rw   = wid * 32;

    // stage means: 16 KB coalesced copy; 8B chunk c of row r at c ^ ((r>>2)&3)
    {
        const unsigned long long* src = (const unsigned long long*)mf8;
        #pragma unroll
        for (int j = 0; j < 8; ++j) {
            const int c = tid + j * 256;       // 8B-chunk index 0..2047
            const int r = c >> 2, ch = c & 3;
            *(unsigned long long*)&mlds[r * 32 + ((ch ^ ((r >> 2) & 3)) << 3)] = src[c];
        }
    }

    // in-block unnormalized weights + start of lse
    const float l0 = logits[b * Kc + tid];
    const float l1 = logits[b * Kc + tid + 256];
    wlds[tid]       = EXP2F((l0 - 0.5f * m2buf[tid])       * LOG2E);
    wlds[tid + 256] = EXP2F((l1 - 0.5f * m2buf[tid + 256]) * LOG2E);

    float mx = fmaxf(l0, l1);
    #pragma unroll
    for (int off = 32; off >= 1; off >>= 1) mx = fmaxf(mx, __shfl_xor(mx, off));
    if (lane == 0) red[wid] = mx;

    // x A-fragments: row = rw + n; lane covers floats [8h..8h+7] (lo) and
    // [16+8h..16+8h+7] (hi). Union over h = full row.
    const int row = rw + n;
    long a_lo, a_hi;
    {
        const float4* xr = (const float4*)(x + ((size_t)b * Sc + s0 + row) * Dc);
        float4 v0 = xr[2 * h], v1 = xr[2 * h + 1];        // lo half
        float4 w0 = xr[4 + 2 * h], w1 = xr[5 + 2 * h];    // hi half
        int2 A;
        A.x = pkfp8<false>(v0.x * LOG2E, v0.y * LOG2E, 0);
        A.x = pkfp8<true >(v0.z * LOG2E, v0.w * LOG2E, A.x);
        A.y = pkfp8<false>(v1.x * LOG2E, v1.y * LOG2E, 0);
        A.y = pkfp8<true >(v1.z * LOG2E, v1.w * LOG2E, A.y);
        a_lo = *(const long*)&A;
        A.x = pkfp8<false>(w0.x * LOG2E, w0.y * LOG2E, 0);
        A.x = pkfp8<true >(w0.z * LOG2E, w0.w * LOG2E, A.x);
        A.y = pkfp8<false>(w1.x * LOG2E, w1.y * LOG2E, 0);
        A.y = pkfp8<true >(w1.z * LOG2E, w1.w * LOG2E, A.y);
        a_hi = *(const long*)&A;
        float p = v0.x*v0.x + v0.y*v0.y + v0.z*v0.z + v0.w*v0.w
                + v1.x*v1.x + v1.y*v1.y + v1.z*v1.z + v1.w*v1.w
                + w0.x*w0.x + w0.y*w0.y + w0.z*w0.z + w0.w*w0.w
                + w1.x*w1.x + w1.y*w1.y + w1.z*w1.z + w1.w*w1.w;
        p += __shfl_xor(p, 32);               // combine the two K-halves
        if (h == 0) x2p[row] = p;
    }
    __syncthreads();

    // finish lse (max across waves parked in red[0..3])
    const float mxb = fmaxf(fmaxf(red[0], red[1]), fmaxf(red[2], red[3]));
    float sm = EXP2F((l0 - mxb) * LOG2E) + EXP2F((l1 - mxb) * LOG2E);
    #pragma unroll
    for (int off = 32; off >= 1; off >>= 1) sm += __shfl_xor(sm, off);
    if (lane == 0) red[4 + wid] = sm;

    // B-frag base addrs: row n, logical chunk h (lo) / 2+h (hi), XOR (n>>2)&3.
    // kt advances by 32 rows * 32 B = 1024 B.
    const int s   = (n >> 2) & 3;
    const int vlo = n * 32 + ((h ^ s) << 3);
    const int vhi = vlo ^ 16;                 // chunk (2+h)^s = (h^s)^2 -> ^16 bytes

    const f32x16 zero = {0.f,0.f,0.f,0.f,0.f,0.f,0.f,0.f,
                         0.f,0.f,0.f,0.f,0.f,0.f,0.f,0.f};
    float acc[16] = {};

    #pragma unroll 4
    for (int kt = 0; kt < 16; ++kt) {
        const long b_lo = *(const long*)&mlds[vlo + kt * 1024];
        const long b_hi = *(const long*)&mlds[vhi + kt * 1024];
        const float wv  = wlds[kt * 32 + n];   // bcast pair-read, conflict-free
        f32x16 d = __builtin_amdgcn_mfma_f32_32x32x16_fp8_fp8(a_lo, b_lo, zero, 0, 0, 0);
        d = __builtin_amdgcn_mfma_f32_32x32x16_fp8_fp8(a_hi, b_hi, d, 0, 0, 0);
        #pragma unroll
        for (int r = 0; r < 16; ++r)
            acc[r] = fmaf(wv, EXP2F(d[r]), acc[r]);
    }
    __syncthreads();                          // red[4..7] ready
    const float lse  = mxb + LN2 * LOG2F(red[4] + red[5] + red[6] + red[7]);
    const float base = LOG_NORM + lse;

    // epilogue: sum over 32 k-cols (lanes within each 32-half), write 32 rows.
    // C/D: col=lane&31, row m = (r&3) + 8*(r>>2) + 4*h
    #pragma unroll
    for (int r = 0; r < 16; ++r) {
        float v = acc[r];
        v += __shfl_xor(v, 1); v += __shfl_xor(v, 2);
        v += __shfl_xor(v, 4); v += __shfl_xor(v, 8); v += __shfl_xor(v, 16);
        if (n == 0) {
            const int m = (r & 3) + 8 * (r >> 2) + 4 * h;
            out[(size_t)b * Sc + s0 + rw + m] =
                0.5f * x2p[rw + m] + base - LN2 * LOG2F(v);
        }
    }
}

extern "C" void kernel_launch(void* const* d_in, const int* in_sizes, int n_in,
                              void* d_out, int out_size, void* d_ws, size_t ws_size,
                              hipStream_t stream) {
    const float* x      = (const float*)d_in[0];
    const float* logits = (const float*)d_in[1];
    const float* means  = (const float*)d_in[2];
    float* out = (float*)d_out;
    (void)in_sizes; (void)n_in; (void)out_size; (void)ws_size;

    unsigned short* mf8   = (unsigned short*)d_ws;             // 16 KB (8192 u16)
    float*          m2buf = (float*)((char*)d_ws + 16384);     //  2 KB

    hipLaunchKernelGGL(gm_m2f8, dim3(32), dim3(256), 0, stream, means, mf8, m2buf);
    hipLaunchKernelGGL(gm_main, dim3(Bc * (Sc / ST)), dim3(256), 0, stream,
                       x, logits, m2buf, mf8, out);
}

// Round 14
// 90.023 us; speedup vs baseline: 6.5291x; 1.0515x over previous
//
#include <hip/hip_runtime.h>
#include <math.h>

// Problem constants (fixed by setup_inputs)
constexpr int Bc = 256, Sc = 1024, Dc = 32, Kc = 512;
constexpr int ST = 128;                      // s-rows per main block (measured best)
constexpr float LOG2E    = 1.4426950408889634f;
constexpr float LN2      = 0.6931471805599453f;
constexpr float LOG_NORM = 29.40603306051f;  // D * 0.5 * log(2*pi)

typedef __attribute__((ext_vector_type(4))) float f32x4;

#if __has_builtin(__builtin_amdgcn_exp2f)
#define EXP2F(v) __builtin_amdgcn_exp2f(v)
#else
#define EXP2F(v) exp2f(v)
#endif
#if __has_builtin(__builtin_amdgcn_logf)
#define LOG2F(v) __builtin_amdgcn_logf(v)
#else
#define LOG2F(v) log2f(v)
#endif

// pack 2 f32 -> 2 e4m3 bytes; word_sel is a template constant.
template <bool HI>
__device__ __forceinline__ int pkfp8(float a, float b, int old) {
    return __builtin_amdgcn_cvt_pk_fp8_f32(a, b, old, HI);
}

// Swizzled LDS byte offset for fp8 means: row = k (32 B), chunk = 8B octet 0..3,
// XOR (row>>2)&3. Hot-loop b64 reads are phase-optimal (4 phases x 32 banks).
__device__ __forceinline__ int swz8(int row, int chunk) {
    return row * 32 + ((chunk ^ ((row >> 2) & 3)) << 3);
}

// ---------------- tiny prep: means -> e4m3 + m2buf[512] ----------------
// grid(32) x 256; thread owns 2 consecutive floats (coalesced 8B reads).
__global__ __launch_bounds__(256)
void gm_m2f8(const float* __restrict__ means,
             unsigned short* __restrict__ mf8, float* __restrict__ m2buf)
{
    const int t  = blockIdx.x * 256 + threadIdx.x;   // 0..8191 (pairs)
    const float v0 = means[2 * t];
    const float v1 = means[2 * t + 1];
    mf8[t] = (unsigned short)(pkfp8<false>(v0, v1, 0) & 0xffff);
    float sq = v0 * v0 + v1 * v1;
    #pragma unroll
    for (int off = 1; off <= 8; off <<= 1) sq += __shfl_xor(sq, off);
    if ((threadIdx.x & 15) == 0) m2buf[t >> 4] = sq;   // 16 pair-threads per row
}

// ---------------- main kernel ----------------
// grid(2048), 256 threads = 4 waves; wave owns 32 s-rows (2 x 16-row subtiles).
// x-loads issued FIRST so their ~900cy HBM latency hides under means staging.
//   acc = sum_k 2^((l_k-0.5*m2_k)*log2e) * 2^((x*log2e).mu_k)
//   nll = 0.5*x^2 + LOG_NORM + lse - ln2*log2(acc)
__global__ __launch_bounds__(256, 6)
void gm_main(const float* __restrict__ x, const float* __restrict__ logits,
             const float* __restrict__ m2buf, const unsigned short* __restrict__ mf8,
             float* __restrict__ out)
{
    __shared__ unsigned char mlds[Kc * 32];   // 16 KB e4m3 means, swizzled
    __shared__ float wlds[Kc];                //  2 KB unnormalized weights
    __shared__ float x2p[ST];                 // 0.5 KB per-row sum(x^2)
    __shared__ float red[8];

    const int tid  = threadIdx.x;
    const int lane = tid & 63;
    const int wid  = tid >> 6;
    const int b    = blockIdx.x >> 3;
    const int s0   = (blockIdx.x & 7) * ST;
    const int q    = lane >> 4;               // k-octet of contraction dim
    const int ln   = lane & 15;
    const int rw   = wid * 32;

    // ---- 1) issue x loads FIRST (cold HBM, longest latency) ----
    const int row0 = rw + ln, row1 = row0 + 16;
    const float4* xp0 = (const float4*)(x + ((size_t)b * Sc + s0 + row0) * Dc) + q * 2;
    const float4* xp1 = (const float4*)(x + ((size_t)b * Sc + s0 + row1) * Dc) + q * 2;
    const float4 v0 = xp0[0], v1 = xp0[1];
    const float4 u0 = xp1[0], u1 = xp1[1];

    // ---- 2) means staging: 16 KB L2-hot copy into swizzled LDS ----
    {
        const unsigned long long* src = (const unsigned long long*)mf8;
        #pragma unroll
        for (int j = 0; j < 8; ++j) {
            const int c = tid + j * 256;       // 8B-chunk index 0..2047
            *(unsigned long long*)&mlds[swz8(c >> 2, c & 3)] = src[c];
        }
    }

    // ---- 3) weights + lse max (trans work overlaps other blocks' loops) ----
    const float l0 = logits[b * Kc + tid];
    const float l1 = logits[b * Kc + tid + 256];
    wlds[tid]       = EXP2F((l0 - 0.5f * m2buf[tid])       * LOG2E);
    wlds[tid + 256] = EXP2F((l1 - 0.5f * m2buf[tid + 256]) * LOG2E);

    float mx = fmaxf(l0, l1);
    #pragma unroll
    for (int off = 32; off >= 1; off >>= 1) mx = fmaxf(mx, __shfl_xor(mx, off));
    if (lane == 0) red[wid] = mx;

    // ---- 4) pack x (loads long retired), x2 partials ----
    long a0, a1;
    {
        int2 A;
        A.x = pkfp8<false>(v0.x * LOG2E, v0.y * LOG2E, 0);
        A.x = pkfp8<true >(v0.z * LOG2E, v0.w * LOG2E, A.x);
        A.y = pkfp8<false>(v1.x * LOG2E, v1.y * LOG2E, 0);
        A.y = pkfp8<true >(v1.z * LOG2E, v1.w * LOG2E, A.y);
        a0 = *(const long*)&A;
        A.x = pkfp8<false>(u0.x * LOG2E, u0.y * LOG2E, 0);
        A.x = pkfp8<true >(u0.z * LOG2E, u0.w * LOG2E, A.x);
        A.y = pkfp8<false>(u1.x * LOG2E, u1.y * LOG2E, 0);
        A.y = pkfp8<true >(u1.z * LOG2E, u1.w * LOG2E, A.y);
        a1 = *(const long*)&A;
    }
    float p0 = v0.x*v0.x + v0.y*v0.y + v0.z*v0.z + v0.w*v0.w
             + v1.x*v1.x + v1.y*v1.y + v1.z*v1.z + v1.w*v1.w;
    float p1 = u0.x*u0.x + u0.y*u0.y + u0.z*u0.z + u0.w*u0.w
             + u1.x*u1.x + u1.y*u1.y + u1.z*u1.z + u1.w*u1.w;
    p0 += __shfl_xor(p0, 16); p0 += __shfl_xor(p0, 32);
    p1 += __shfl_xor(p1, 16); p1 += __shfl_xor(p1, 32);
    if (q == 0) { x2p[row0] = p0; x2p[row1] = p1; }
    __syncthreads();

    // finish lse (max across waves parked in red[0..3])
    const float mxb = fmaxf(fmaxf(red[0], red[1]), fmaxf(red[2], red[3]));
    float sm = EXP2F((l0 - mxb) * LOG2E) + EXP2F((l1 - mxb) * LOG2E);
    #pragma unroll
    for (int off = 32; off >= 1; off >>= 1) sm += __shfl_xor(sm, off);
    if (lane == 0) red[4 + wid] = sm;

    // ---- 5) main loop; swizzle XOR term is kt-invariant: addr = base + kt*512
    const int bbase = ln * 32 + ((q ^ ((ln >> 2) & 3)) << 3);
    const f32x4 zero = {0.f, 0.f, 0.f, 0.f};
    float acc0[4] = {0.f, 0.f, 0.f, 0.f};
    float acc1[4] = {0.f, 0.f, 0.f, 0.f};

    #pragma unroll 4
    for (int kt = 0; kt < 32; ++kt) {
        const long  bfr = *(const long*)&mlds[bbase + kt * 512];
        const float wv  = wlds[kt * 16 + ln];  // bcast across q-groups
        f32x4 d0 = __builtin_amdgcn_mfma_f32_16x16x32_fp8_fp8(a0, bfr, zero, 0, 0, 0);
        f32x4 d1 = __builtin_amdgcn_mfma_f32_16x16x32_fp8_fp8(a1, bfr, zero, 0, 0, 0);
        #pragma unroll
        for (int r = 0; r < 4; ++r) {
            acc0[r] = fmaf(wv, EXP2F(d0[r]), acc0[r]);
            acc1[r] = fmaf(wv, EXP2F(d1[r]), acc1[r]);
        }
    }
    __syncthreads();                          // red[4..7] ready
    const float lse  = mxb + LN2 * LOG2F(red[4] + red[5] + red[6] + red[7]);
    const float base = LOG_NORM + lse;

    // ---- 6) epilogue: reduce 16 k-cols (low-4 lane bits), write ----
    #pragma unroll
    for (int r = 0; r < 4; ++r) {
        float s0v = acc0[r], s1v = acc1[r];
        s0v += __shfl_xor(s0v, 1); s0v += __shfl_xor(s0v, 2);
        s0v += __shfl_xor(s0v, 4); s0v += __shfl_xor(s0v, 8);
        s1v += __shfl_xor(s1v, 1); s1v += __shfl_xor(s1v, 2);
        s1v += __shfl_xor(s1v, 4); s1v += __shfl_xor(s1v, 8);
        if (ln == 0) {
            const int r0 = rw + q * 4 + r;       // C/D row = quad*4 + reg
            const int r1 = r0 + 16;
            out[(size_t)b * Sc + s0 + r0] = 0.5f * x2p[r0] + base - LN2 * LOG2F(s0v);
            out[(size_t)b * Sc + s0 + r1] = 0.5f * x2p[r1] + base - LN2 * LOG2F(s1v);
        }
    }
}

extern "C" void kernel_launch(void* const* d_in, const int* in_sizes, int n_in,
                              void* d_out, int out_size, void* d_ws, size_t ws_size,
                              hipStream_t stream) {
    const float* x      = (const float*)d_in[0];
    const float* logits = (const float*)d_in[1];
    const float* means  = (const float*)d_in[2];
    float* out = (float*)d_out;
    (void)in_sizes; (void)n_in; (void)out_size; (void)ws_size;

    unsigned short* mf8   = (unsigned short*)d_ws;             // 16 KB (8192 u16)
    float*          m2buf = (float*)((char*)d_ws + 16384);     //  2 KB

    hipLaunchKernelGGL(gm_m2f8, dim3(32), dim3(256), 0, stream, means, mf8, m2buf);
    hipLaunchKernelGGL(gm_main, dim3(Bc * (Sc / ST)), dim3(256), 0, stream,
                       x, logits, m2buf, mf8, out);
}